// Round 7
// baseline (204.649 us; speedup 1.0000x reference)
//
#include <hip/hip_runtime.h>
#include <hip/hip_bf16.h>

#define N_NODE 50000
#define N_USED 50000
#define N_EDGE 800000
#define N_REL  8

typedef __bf16 bf16x8 __attribute__((ext_vector_type(8)));
typedef float  f32x4  __attribute__((ext_vector_type(4)));

__device__ __forceinline__ float bf_lo(unsigned u) {
    union { unsigned i; float f; } v; v.i = u << 16; return v.f;
}
__device__ __forceinline__ float bf_hi(unsigned u) {
    union { unsigned i; float f; } v; v.i = u & 0xffff0000u; return v.f;
}
__device__ __forceinline__ unsigned pack2(float a, float b) {
    __hip_bfloat16 ha = __float2bfloat16(a), hb = __float2bfloat16(b);
    unsigned short ua = *reinterpret_cast<unsigned short*>(&ha);
    unsigned short ub = *reinterpret_cast<unsigned short*>(&hb);
    return (unsigned)ua | ((unsigned)ub << 16);
}

// ---- x (fp32, [N_USED][128]) -> xb (bf16) ----
__global__ __launch_bounds__(256) void k_cvt_x(const float* __restrict__ x,
                                               __hip_bfloat16* __restrict__ xb) {
    int i = blockIdx.x * 256 + threadIdx.x;
    float4 v = reinterpret_cast<const float4*>(x)[i];
    __hip_bfloat16 h0 = __float2bfloat16(v.x);
    __hip_bfloat16 h1 = __float2bfloat16(v.y);
    __hip_bfloat16 h2 = __float2bfloat16(v.z);
    __hip_bfloat16 h3 = __float2bfloat16(v.w);
    ushort4 o;
    o.x = *reinterpret_cast<unsigned short*>(&h0);
    o.y = *reinterpret_cast<unsigned short*>(&h1);
    o.z = *reinterpret_cast<unsigned short*>(&h2);
    o.w = *reinterpret_cast<unsigned short*>(&h3);
    reinterpret_cast<ushort4*>(xb)[i] = o;
}

// ---- W [r][c][h] fp32 -> Wt [r][h][c] bf16 ----
__global__ __launch_bounds__(256) void k_cvt_w(const float* __restrict__ w,
                                               __hip_bfloat16* __restrict__ wt) {
    int i = blockIdx.x * 256 + threadIdx.x;       // 131072 elems
    int r = i >> 14, c = (i >> 7) & 127, h = i & 127;
    wt[(((size_t)r << 7) + h) * 128 + c] = __float2bfloat16(w[i]);
}

// ---- stage A: aggregate-first segment sum on x ----
// 4 waves/block, wave = one node, NO barriers, wave-private LDS accumulator.
// 16-deep edge batches: one vmcnt stall per 16 edges instead of per 8.
__global__ __launch_bounds__(256) void k_agg(const __hip_bfloat16* __restrict__ xb,
                                             const int* __restrict__ ptr,
                                             const int* __restrict__ idx,
                                             const int* __restrict__ rel,
                                             __hip_bfloat16* __restrict__ agg) {
    __shared__ float aggf[4 * N_REL * 128];       // 16 KB, wave-private 4KB regions

    const int lane = threadIdx.x & 63;
    const int w    = threadIdx.x >> 6;
    const int node = blockIdx.x * 4 + w;          // 12500*4 = 50000 exact
    float* mine = &aggf[w << 10];

    // zero own region (no sync needed — wave-private)
    const f32x4 z4 = {0.f, 0.f, 0.f, 0.f};
#pragma unroll
    for (int k = 0; k < 4; ++k)
        *reinterpret_cast<f32x4*>(&mine[(lane << 2) + (k << 8)]) = z4;

    const int e0 = ptr[node];
    const int e1 = ptr[node + 1];
    const unsigned* xu = (const unsigned*)xb;     // lane owns ch {2l, 2l+1}

    for (int e = e0; e < e1; e += 16) {
        const int m = e1 - e;
        int ib[16], rb[16];
#pragma unroll
        for (int b = 0; b < 16; ++b) {
            int ee = (b < m) ? e + b : e0;        // uniform clamp
            ib[b] = idx[ee];
            rb[b] = rel[ee];
        }
        unsigned ub[16];
#pragma unroll
        for (int b = 0; b < 16; ++b)
            ub[b] = xu[(size_t)ib[b] * 64 + lane];
#pragma unroll
        for (int b = 0; b < 16; ++b) {
            if (b < m) {                          // uniform branch
                float* p = mine + (rb[b] << 7);
                float vlo = p[lane], vhi = p[64 + lane];
                p[lane]      = vlo + bf_lo(ub[b]);
                p[64 + lane] = vhi + bf_hi(ub[b]);
            }
        }
    }

    // pack to bf16, write agg row (node): 8 rels x 256B coalesced
    unsigned* ao = reinterpret_cast<unsigned*>(agg) + (size_t)node * 512 + lane;
#pragma unroll
    for (int r = 0; r < N_REL; ++r) {
        const float* p = mine + (r << 7);
        ao[r << 6] = pack2(p[lane], p[64 + lane]);
    }
}

// ---- stage B: out[50000][128] = agg[50000][1024] @ Wstack[1024][128] ----
// M=16 rows per wave -> 3125 waves (782 blocks of 4 waves) for latency hiding.
__global__ __launch_bounds__(256, 4) void k_gemm2(const __hip_bfloat16* __restrict__ agg,
                                                  const __hip_bfloat16* __restrict__ wt,
                                                  float* __restrict__ out) {
    const int lane = threadIdx.x & 63;
    const int w    = threadIdx.x >> 6;
    const int gw   = blockIdx.x * 4 + w;          // global wave id
    const int n0   = gw * 16;
    if (n0 >= N_NODE) return;
    const int rlo  = lane & 15, khi = lane >> 4;

    f32x4 acc[8];
    const f32x4 zero = {0.f, 0.f, 0.f, 0.f};
#pragma unroll
    for (int nc = 0; nc < 8; ++nc) acc[nc] = zero;

    const int arow = n0 + rlo;                    // < 50000 always for active waves
#pragma unroll
    for (int r = 0; r < N_REL; ++r) {
        const __hip_bfloat16* ap = agg + (((size_t)arow << 3) + r) * 128 + (khi << 3);
        bf16x8 a[4];
#pragma unroll
        for (int kc = 0; kc < 4; ++kc)
            a[kc] = *reinterpret_cast<const bf16x8*>(ap + kc * 32);
        const __hip_bfloat16* wr = wt + ((size_t)r << 14);     // [h][c]
#pragma unroll
        for (int nc = 0; nc < 8; ++nc) {
#pragma unroll
            for (int kc = 0; kc < 4; ++kc) {
                bf16x8 b = *reinterpret_cast<const bf16x8*>(
                    wr + ((size_t)(nc * 16 + rlo) << 7) + kc * 32 + (khi << 3));
                acc[nc] = __builtin_amdgcn_mfma_f32_16x16x32_bf16(a[kc], b, acc[nc], 0, 0, 0);
            }
        }
    }
    // C/D: col = lane&15 (h within nc), row = (lane>>4)*4 + j (node)
#pragma unroll
    for (int j = 0; j < 4; ++j) {
        int n = n0 + (khi << 2) + j;
        if (n < N_NODE) {
            float* dst = out + ((size_t)n << 7) + rlo;
#pragma unroll
            for (int nc = 0; nc < 8; ++nc)
                dst[nc << 4] = acc[nc][j];
        }
    }
}

// ---- fallback (tiny workspace): direct fp32 compute, slow but correct ----
__global__ __launch_bounds__(256) void k_direct(const float* __restrict__ x,
                                                const float* __restrict__ w,
                                                const int* __restrict__ ptr,
                                                const int* __restrict__ idx,
                                                const int* __restrict__ rel,
                                                float* __restrict__ out) {
    const int lane = threadIdx.x & 63;
    const int s = blockIdx.x * 4 + (threadIdx.x >> 6);
    if (s >= N_NODE) return;
    const int e0 = ptr[s], e1 = ptr[s + 1];
    const int h = lane * 2;
    float ax = 0.f, ay = 0.f;
    for (int e = e0; e < e1; ++e) {
        const float* xr = x + (size_t)idx[e] * 128;
        const float* wr = w + (size_t)rel[e] * 16384 + h;
        for (int c = 0; c < 128; ++c) {
            float xv = xr[c];
            ax += xv * wr[(size_t)c * 128];
            ay += xv * wr[(size_t)c * 128 + 1];
        }
    }
    float2 o = {ax, ay};
    reinterpret_cast<float2*>(out + (size_t)s * 128)[lane] = o;
}

extern "C" void kernel_launch(void* const* d_in, const int* in_sizes, int n_in,
                              void* d_out, int out_size, void* d_ws, size_t ws_size,
                              hipStream_t stream) {
    const float* x   = (const float*)d_in[0];
    const float* w   = (const float*)d_in[1];
    const int*   ptr = (const int*)d_in[2];
    const int*   idx = (const int*)d_in[3];
    const int*   rel = (const int*)d_in[4];
    float*       out = (float*)d_out;

    const size_t off_xb  = 0;                       // 12,800,000 B
    const size_t off_wt  = 12800000;                //    262,144 B
    const size_t off_agg = 13062144;                // 102,400,000 B
    const size_t need    = off_agg + (size_t)N_NODE * N_REL * 128 * 2;

    if (ws_size >= need) {
        __hip_bfloat16* xb  = (__hip_bfloat16*)((char*)d_ws + off_xb);
        __hip_bfloat16* wt  = (__hip_bfloat16*)((char*)d_ws + off_wt);
        __hip_bfloat16* agg = (__hip_bfloat16*)((char*)d_ws + off_agg);
        k_cvt_x<<<6250, 256, 0, stream>>>(x, xb);
        k_cvt_w<<<512, 256, 0, stream>>>(w, wt);
        k_agg<<<N_NODE / 4, 256, 0, stream>>>(xb, ptr, idx, rel, agg);
        k_gemm2<<<(3125 + 3) / 4, 256, 0, stream>>>(agg, wt, out);
    } else {
        k_direct<<<12500, 256, 0, stream>>>(x, w, ptr, idx, rel, out);
    }
}

// Round 8
// 163.563 us; speedup vs baseline: 1.2512x; 1.2512x over previous
//
#include <hip/hip_runtime.h>
#include <hip/hip_bf16.h>

#define N_NODE 50000
#define N_USED 50000
#define N_EDGE 800000
#define N_REL  8

typedef __bf16 bf16x8 __attribute__((ext_vector_type(8)));
typedef float  f32x4  __attribute__((ext_vector_type(4)));

__device__ __forceinline__ float bf_lo(unsigned u) {
    union { unsigned i; float f; } v; v.i = u << 16; return v.f;
}
__device__ __forceinline__ float bf_hi(unsigned u) {
    union { unsigned i; float f; } v; v.i = u & 0xffff0000u; return v.f;
}
__device__ __forceinline__ unsigned pack2(float a, float b) {
    __hip_bfloat16 ha = __float2bfloat16(a), hb = __float2bfloat16(b);
    unsigned short ua = *reinterpret_cast<unsigned short*>(&ha);
    unsigned short ub = *reinterpret_cast<unsigned short*>(&hb);
    return (unsigned)ua | ((unsigned)ub << 16);
}

// ---- x (fp32, [N_USED][128]) -> xb (bf16) ----
__global__ __launch_bounds__(256) void k_cvt_x(const float* __restrict__ x,
                                               __hip_bfloat16* __restrict__ xb) {
    int i = blockIdx.x * 256 + threadIdx.x;
    float4 v = reinterpret_cast<const float4*>(x)[i];
    __hip_bfloat16 h0 = __float2bfloat16(v.x);
    __hip_bfloat16 h1 = __float2bfloat16(v.y);
    __hip_bfloat16 h2 = __float2bfloat16(v.z);
    __hip_bfloat16 h3 = __float2bfloat16(v.w);
    ushort4 o;
    o.x = *reinterpret_cast<unsigned short*>(&h0);
    o.y = *reinterpret_cast<unsigned short*>(&h1);
    o.z = *reinterpret_cast<unsigned short*>(&h2);
    o.w = *reinterpret_cast<unsigned short*>(&h3);
    reinterpret_cast<ushort4*>(xb)[i] = o;
}

// ---- W [r][c][h] fp32 -> Wt [r][h][c] bf16 ----
__global__ __launch_bounds__(256) void k_cvt_w(const float* __restrict__ w,
                                               __hip_bfloat16* __restrict__ wt) {
    int i = blockIdx.x * 256 + threadIdx.x;       // 131072 elems
    int r = i >> 14, c = (i >> 7) & 127, h = i & 127;
    wt[(((size_t)r << 7) + h) * 128 + c] = __float2bfloat16(w[i]);
}

// ---- stage A: aggregate-first segment sum on x ----
// 4 waves/block, wave = one node, NO barriers, wave-private LDS accumulator.
__global__ __launch_bounds__(256) void k_agg(const __hip_bfloat16* __restrict__ xb,
                                             const int* __restrict__ ptr,
                                             const int* __restrict__ idx,
                                             const int* __restrict__ rel,
                                             __hip_bfloat16* __restrict__ agg) {
    __shared__ float aggf[4 * N_REL * 128];       // 16 KB, wave-private 4KB regions

    const int lane = threadIdx.x & 63;
    const int w    = threadIdx.x >> 6;
    const int node = blockIdx.x * 4 + w;          // 12500*4 = 50000 exact
    float* mine = &aggf[w << 10];

    const f32x4 z4 = {0.f, 0.f, 0.f, 0.f};
#pragma unroll
    for (int k = 0; k < 4; ++k)
        *reinterpret_cast<f32x4*>(&mine[(lane << 2) + (k << 8)]) = z4;

    const int e0 = ptr[node];
    const int e1 = ptr[node + 1];
    const unsigned* xu = (const unsigned*)xb;     // lane owns ch {2l, 2l+1}

    for (int e = e0; e < e1; e += 16) {
        const int m = e1 - e;
        int ib[16], rb[16];
#pragma unroll
        for (int b = 0; b < 16; ++b) {
            int ee = (b < m) ? e + b : e0;        // uniform clamp
            ib[b] = idx[ee];
            rb[b] = rel[ee];
        }
        unsigned ub[16];
#pragma unroll
        for (int b = 0; b < 16; ++b)
            ub[b] = xu[(size_t)ib[b] * 64 + lane];
#pragma unroll
        for (int b = 0; b < 16; ++b) {
            if (b < m) {                          // uniform branch
                float* p = mine + (rb[b] << 7);
                float vlo = p[lane], vhi = p[64 + lane];
                p[lane]      = vlo + bf_lo(ub[b]);
                p[64 + lane] = vhi + bf_hi(ub[b]);
            }
        }
    }

    // pack to bf16, write agg row (node): 8 rels x 256B coalesced
    unsigned* ao = reinterpret_cast<unsigned*>(agg) + (size_t)node * 512 + lane;
#pragma unroll
    for (int r = 0; r < N_REL; ++r) {
        const float* p = mine + (r << 7);
        ao[r << 6] = pack2(p[lane], p[64 + lane]);
    }
}

// ---- stage B: out[50000][128] = agg[50000][1024] @ Wstack[1024][128] ----
// N-split x2: each wave M=32 rows, N=64 cols (half), K=1024.
// 3126 active waves (~3/SIMD); disjoint outputs, no combine.
__global__ __launch_bounds__(256, 4) void k_gemm2(const __hip_bfloat16* __restrict__ agg,
                                                  const __hip_bfloat16* __restrict__ wt,
                                                  float* __restrict__ out) {
    const int lane = threadIdx.x & 63;
    const int w    = threadIdx.x >> 6;
    const int gw   = blockIdx.x * 4 + w;          // global wave id
    const int half = gw & 1;                      // N-half: cols [half*64, +64)
    const int n0   = (gw >> 1) * 32;              // row base
    if (n0 >= N_NODE) return;
    const int rlo  = lane & 15, khi = lane >> 4;
    const int hbase = (half << 6);

    f32x4 acc[2][4];
    const f32x4 zero = {0.f, 0.f, 0.f, 0.f};
#pragma unroll
    for (int rc = 0; rc < 2; ++rc)
#pragma unroll
        for (int nc = 0; nc < 4; ++nc) acc[rc][nc] = zero;

#pragma unroll
    for (int r = 0; r < N_REL; ++r) {
        bf16x8 a[2][4];
#pragma unroll
        for (int rc = 0; rc < 2; ++rc) {
            int row = n0 + rc * 16 + rlo;
            if (row >= N_NODE) row = N_NODE - 1;              // clamp; store guarded
            const __hip_bfloat16* ap = agg + (((size_t)row << 3) + r) * 128 + (khi << 3);
#pragma unroll
            for (int kc = 0; kc < 4; ++kc)
                a[rc][kc] = *reinterpret_cast<const bf16x8*>(ap + kc * 32);
        }
        const __hip_bfloat16* wr = wt + ((size_t)r << 14);     // [h][c]
#pragma unroll
        for (int nc = 0; nc < 4; ++nc) {
            const int h = hbase + nc * 16 + rlo;
#pragma unroll
            for (int kc = 0; kc < 4; ++kc) {
                bf16x8 b = *reinterpret_cast<const bf16x8*>(
                    wr + ((size_t)h << 7) + kc * 32 + (khi << 3));
                acc[0][nc] = __builtin_amdgcn_mfma_f32_16x16x32_bf16(a[0][kc], b, acc[0][nc], 0, 0, 0);
                acc[1][nc] = __builtin_amdgcn_mfma_f32_16x16x32_bf16(a[1][kc], b, acc[1][nc], 0, 0, 0);
            }
        }
    }
    // C/D: col = lane&15 (h within nc), row = (lane>>4)*4 + j
#pragma unroll
    for (int rc = 0; rc < 2; ++rc) {
#pragma unroll
        for (int j = 0; j < 4; ++j) {
            int n = n0 + rc * 16 + (khi << 2) + j;
            if (n < N_NODE) {
                float* dst = out + ((size_t)n << 7) + hbase + rlo;
#pragma unroll
                for (int nc = 0; nc < 4; ++nc)
                    dst[nc << 4] = acc[rc][nc][j];
            }
        }
    }
}

// ---- fallback (tiny workspace): direct fp32 compute, slow but correct ----
__global__ __launch_bounds__(256) void k_direct(const float* __restrict__ x,
                                                const float* __restrict__ w,
                                                const int* __restrict__ ptr,
                                                const int* __restrict__ idx,
                                                const int* __restrict__ rel,
                                                float* __restrict__ out) {
    const int lane = threadIdx.x & 63;
    const int s = blockIdx.x * 4 + (threadIdx.x >> 6);
    if (s >= N_NODE) return;
    const int e0 = ptr[s], e1 = ptr[s + 1];
    const int h = lane * 2;
    float ax = 0.f, ay = 0.f;
    for (int e = e0; e < e1; ++e) {
        const float* xr = x + (size_t)idx[e] * 128;
        const float* wr = w + (size_t)rel[e] * 16384 + h;
        for (int c = 0; c < 128; ++c) {
            float xv = xr[c];
            ax += xv * wr[(size_t)c * 128];
            ay += xv * wr[(size_t)c * 128 + 1];
        }
    }
    float2 o = {ax, ay};
    reinterpret_cast<float2*>(out + (size_t)s * 128)[lane] = o;
}

extern "C" void kernel_launch(void* const* d_in, const int* in_sizes, int n_in,
                              void* d_out, int out_size, void* d_ws, size_t ws_size,
                              hipStream_t stream) {
    const float* x   = (const float*)d_in[0];
    const float* w   = (const float*)d_in[1];
    const int*   ptr = (const int*)d_in[2];
    const int*   idx = (const int*)d_in[3];
    const int*   rel = (const int*)d_in[4];
    float*       out = (float*)d_out;

    const size_t off_xb  = 0;                       // 12,800,000 B
    const size_t off_wt  = 12800000;                //    262,144 B
    const size_t off_agg = 13062144;                // 102,400,000 B
    const size_t need    = off_agg + (size_t)N_NODE * N_REL * 128 * 2;

    if (ws_size >= need) {
        __hip_bfloat16* xb  = (__hip_bfloat16*)((char*)d_ws + off_xb);
        __hip_bfloat16* wt  = (__hip_bfloat16*)((char*)d_ws + off_wt);
        __hip_bfloat16* agg = (__hip_bfloat16*)((char*)d_ws + off_agg);
        k_cvt_x<<<6250, 256, 0, stream>>>(x, xb);
        k_cvt_w<<<512, 256, 0, stream>>>(w, wt);
        k_agg<<<N_NODE / 4, 256, 0, stream>>>(xb, ptr, idx, rel, agg);
        // 1563 row-groups * 2 N-halves = 3126 waves; 4 waves/block
        k_gemm2<<<(3126 + 3) / 4, 256, 0, stream>>>(agg, wt, out);
    } else {
        k_direct<<<12500, 256, 0, stream>>>(x, w, ptr, idx, rel, out);
    }
}

// Round 9
// 161.496 us; speedup vs baseline: 1.2672x; 1.0128x over previous
//
#include <hip/hip_runtime.h>
#include <hip/hip_bf16.h>

#define N_NODE 50000
#define N_USED 50000
#define N_EDGE 800000
#define N_REL  8

typedef __bf16 bf16x8 __attribute__((ext_vector_type(8)));
typedef float  f32x4  __attribute__((ext_vector_type(4)));

__device__ __forceinline__ float bf_lo(unsigned u) {
    union { unsigned i; float f; } v; v.i = u << 16; return v.f;
}
__device__ __forceinline__ float bf_hi(unsigned u) {
    union { unsigned i; float f; } v; v.i = u & 0xffff0000u; return v.f;
}
__device__ __forceinline__ unsigned pack2(float a, float b) {
    __hip_bfloat16 ha = __float2bfloat16(a), hb = __float2bfloat16(b);
    unsigned short ua = *reinterpret_cast<unsigned short*>(&ha);
    unsigned short ub = *reinterpret_cast<unsigned short*>(&hb);
    return (unsigned)ua | ((unsigned)ub << 16);
}

// ---- x (fp32, [N_USED][128]) -> xb (bf16) ----
__global__ __launch_bounds__(256) void k_cvt_x(const float* __restrict__ x,
                                               __hip_bfloat16* __restrict__ xb) {
    int i = blockIdx.x * 256 + threadIdx.x;
    float4 v = reinterpret_cast<const float4*>(x)[i];
    __hip_bfloat16 h0 = __float2bfloat16(v.x);
    __hip_bfloat16 h1 = __float2bfloat16(v.y);
    __hip_bfloat16 h2 = __float2bfloat16(v.z);
    __hip_bfloat16 h3 = __float2bfloat16(v.w);
    ushort4 o;
    o.x = *reinterpret_cast<unsigned short*>(&h0);
    o.y = *reinterpret_cast<unsigned short*>(&h1);
    o.z = *reinterpret_cast<unsigned short*>(&h2);
    o.w = *reinterpret_cast<unsigned short*>(&h3);
    reinterpret_cast<ushort4*>(xb)[i] = o;
}

// ---- W [r][c][h] fp32 -> Wt [r][h][c] bf16 ----
__global__ __launch_bounds__(256) void k_cvt_w(const float* __restrict__ w,
                                               __hip_bfloat16* __restrict__ wt) {
    int i = blockIdx.x * 256 + threadIdx.x;       // 131072 elems
    int r = i >> 14, c = (i >> 7) & 127, h = i & 127;
    wt[(((size_t)r << 7) + h) * 128 + c] = __float2bfloat16(w[i]);
}

// ---- stage A: aggregate-first segment sum on x ----
// Grid-stride over nodes (2048 blocks stay resident; waves overlap gather
// latency). Wave-private LDS accumulator, no barriers, no atomics.
__global__ __launch_bounds__(256, 4) void k_agg(const __hip_bfloat16* __restrict__ xb,
                                                const int* __restrict__ ptr,
                                                const int* __restrict__ idx,
                                                const int* __restrict__ rel,
                                                __hip_bfloat16* __restrict__ agg) {
    __shared__ float aggf[4 * N_REL * 128];       // 16 KB, wave-private 4KB regions

    const int lane = threadIdx.x & 63;
    const int w    = threadIdx.x >> 6;
    const int gw   = blockIdx.x * 4 + w;          // 8192 persistent waves
    float* mine = &aggf[w << 10];
    const unsigned* xu = (const unsigned*)xb;     // lane owns ch {2l, 2l+1}
    const f32x4 z4 = {0.f, 0.f, 0.f, 0.f};

    for (int node = gw; node < N_NODE; node += 8192) {
#pragma unroll
        for (int k = 0; k < 4; ++k)
            *reinterpret_cast<f32x4*>(&mine[(lane << 2) + (k << 8)]) = z4;

        const int e0 = ptr[node];
        const int e1 = ptr[node + 1];

        for (int e = e0; e < e1; e += 16) {
            const int m = e1 - e;
            int ib[16], rb[16];
#pragma unroll
            for (int b = 0; b < 16; ++b) {
                int ee = (b < m) ? e + b : e0;    // uniform clamp
                ib[b] = idx[ee];
                rb[b] = rel[ee];
            }
            unsigned ub[16];
#pragma unroll
            for (int b = 0; b < 16; ++b)
                ub[b] = xu[(size_t)ib[b] * 64 + lane];
#pragma unroll
            for (int b = 0; b < 16; ++b) {
                if (b < m) {                      // uniform branch
                    float* p = mine + (rb[b] << 7);
                    float vlo = p[lane], vhi = p[64 + lane];
                    p[lane]      = vlo + bf_lo(ub[b]);
                    p[64 + lane] = vhi + bf_hi(ub[b]);
                }
            }
        }

        // pack to bf16, write agg row: 8 rels x 256B coalesced
        unsigned* ao = reinterpret_cast<unsigned*>(agg) + (size_t)node * 512 + lane;
#pragma unroll
        for (int r = 0; r < N_REL; ++r) {
            const float* p = mine + (r << 7);
            ao[r << 6] = pack2(p[lane], p[64 + lane]);
        }
    }
}

// ---- stage B: out[50000][128] = agg[50000][1024] @ Wstack[1024][128] ----
// 782 blocks = 391 M-groups (128 rows) x 2 N-halves (64 cols).
// B (Wt) staged per-rel in LDS with XOR swizzle (conflict-free ds_read_b128);
// next rel's tile prefetched into regs during MFMA (issue-early/write-late).
__global__ __launch_bounds__(256, 2)
void k_gemm2(const __hip_bfloat16* __restrict__ agg,
             const __hip_bfloat16* __restrict__ wt,
             float* __restrict__ out) {
    __shared__ unsigned char ldsb[16384];         // one 64h x 128c bf16 tile

    const int tid  = threadIdx.x;
    const int lane = tid & 63;
    const int w    = tid >> 6;
    const int mg   = blockIdx.x >> 1;
    const int half = blockIdx.x & 1;
    const int n0   = mg * 128 + w * 32;
    const int rlo  = lane & 15, khi = lane >> 4;
    const int hbase = half << 6;

    int ar0 = n0 + rlo;       if (ar0 >= N_NODE) ar0 = N_NODE - 1;
    int ar1 = n0 + 16 + rlo;  if (ar1 >= N_NODE) ar1 = N_NODE - 1;

    // staging: thread covers 4 x 16B chunks of the 16 KB tile
    unsigned so[4], sw[4];
#pragma unroll
    for (int i = 0; i < 4; ++i) {
        unsigned o  = i * 4096 + tid * 16;        // linear-logical byte in tile
        unsigned hh = o >> 8;                     // local h row 0..63
        so[i] = ((unsigned)(hbase + hh) << 7) + ((o & 255) >> 1);   // elems within rel
        sw[i] = o ^ ((hh & 7) << 4);              // swizzled LDS byte
    }
    uint4 st[4];
#pragma unroll
    for (int i = 0; i < 4; ++i)                   // prologue: tile r=0
        st[i] = *reinterpret_cast<const uint4*>(wt + so[i]);

    f32x4 acc[2][4];
    const f32x4 zero = {0.f, 0.f, 0.f, 0.f};
#pragma unroll
    for (int rc = 0; rc < 2; ++rc)
#pragma unroll
        for (int nc = 0; nc < 4; ++nc) acc[rc][nc] = zero;

    for (int r = 0; r < N_REL; ++r) {
        __syncthreads();                          // prev reads done
#pragma unroll
        for (int i = 0; i < 4; ++i)
            *reinterpret_cast<uint4*>(ldsb + sw[i]) = st[i];
        __syncthreads();                          // tile r visible
        if (r < N_REL - 1) {                      // prefetch tile r+1
            const __hip_bfloat16* wsrc = wt + ((size_t)(r + 1) << 14);
#pragma unroll
            for (int i = 0; i < 4; ++i)
                st[i] = *reinterpret_cast<const uint4*>(wsrc + so[i]);
        }
        // A fragments (direct global, L3-hot)
        const __hip_bfloat16* ap0 = agg + ((size_t)ar0 << 10) + (r << 7) + (khi << 3);
        const __hip_bfloat16* ap1 = agg + ((size_t)ar1 << 10) + (r << 7) + (khi << 3);
        bf16x8 a0[4], a1[4];
#pragma unroll
        for (int kc = 0; kc < 4; ++kc) {
            a0[kc] = *reinterpret_cast<const bf16x8*>(ap0 + kc * 32);
            a1[kc] = *reinterpret_cast<const bf16x8*>(ap1 + kc * 32);
        }
#pragma unroll
        for (int nc = 0; nc < 4; ++nc) {
#pragma unroll
            for (int kc = 0; kc < 4; ++kc) {
                unsigned mb = (unsigned)(nc * 4096 + (rlo << 8) + kc * 64 + (khi << 4));
                mb ^= (unsigned)((rlo & 7) << 4); // read-side swizzle
                bf16x8 b = *reinterpret_cast<const bf16x8*>(ldsb + mb);
                acc[0][nc] = __builtin_amdgcn_mfma_f32_16x16x32_bf16(a0[kc], b, acc[0][nc], 0, 0, 0);
                acc[1][nc] = __builtin_amdgcn_mfma_f32_16x16x32_bf16(a1[kc], b, acc[1][nc], 0, 0, 0);
            }
        }
    }
    // C/D: col = lane&15 (h within nc), row = (lane>>4)*4 + j
#pragma unroll
    for (int rc = 0; rc < 2; ++rc) {
#pragma unroll
        for (int j = 0; j < 4; ++j) {
            int n = n0 + rc * 16 + (khi << 2) + j;
            if (n < N_NODE) {
                float* dst = out + ((size_t)n << 7) + hbase + rlo;
#pragma unroll
                for (int nc = 0; nc < 4; ++nc)
                    dst[nc << 4] = acc[rc][nc][j];
            }
        }
    }
}

// ---- fallback (tiny workspace): direct fp32 compute, slow but correct ----
__global__ __launch_bounds__(256) void k_direct(const float* __restrict__ x,
                                                const float* __restrict__ w,
                                                const int* __restrict__ ptr,
                                                const int* __restrict__ idx,
                                                const int* __restrict__ rel,
                                                float* __restrict__ out) {
    const int lane = threadIdx.x & 63;
    const int s = blockIdx.x * 4 + (threadIdx.x >> 6);
    if (s >= N_NODE) return;
    const int e0 = ptr[s], e1 = ptr[s + 1];
    const int h = lane * 2;
    float ax = 0.f, ay = 0.f;
    for (int e = e0; e < e1; ++e) {
        const float* xr = x + (size_t)idx[e] * 128;
        const float* wr = w + (size_t)rel[e] * 16384 + h;
        for (int c = 0; c < 128; ++c) {
            float xv = xr[c];
            ax += xv * wr[(size_t)c * 128];
            ay += xv * wr[(size_t)c * 128 + 1];
        }
    }
    float2 o = {ax, ay};
    reinterpret_cast<float2*>(out + (size_t)s * 128)[lane] = o;
}

extern "C" void kernel_launch(void* const* d_in, const int* in_sizes, int n_in,
                              void* d_out, int out_size, void* d_ws, size_t ws_size,
                              hipStream_t stream) {
    const float* x   = (const float*)d_in[0];
    const float* w   = (const float*)d_in[1];
    const int*   ptr = (const int*)d_in[2];
    const int*   idx = (const int*)d_in[3];
    const int*   rel = (const int*)d_in[4];
    float*       out = (float*)d_out;

    const size_t off_xb  = 0;                       // 12,800,000 B
    const size_t off_wt  = 12800000;                //    262,144 B
    const size_t off_agg = 13062144;                // 102,400,000 B
    const size_t need    = off_agg + (size_t)N_NODE * N_REL * 128 * 2;

    if (ws_size >= need) {
        __hip_bfloat16* xb  = (__hip_bfloat16*)((char*)d_ws + off_xb);
        __hip_bfloat16* wt  = (__hip_bfloat16*)((char*)d_ws + off_wt);
        __hip_bfloat16* agg = (__hip_bfloat16*)((char*)d_ws + off_agg);
        k_cvt_x<<<6250, 256, 0, stream>>>(x, xb);
        k_cvt_w<<<512, 256, 0, stream>>>(w, wt);
        k_agg<<<2048, 256, 0, stream>>>(xb, ptr, idx, rel, agg);
        k_gemm2<<<782, 256, 0, stream>>>(agg, wt, out);
    } else {
        k_direct<<<12500, 256, 0, stream>>>(x, w, ptr, idx, rel, out);
    }
}